// Round 1
// baseline (4008.781 us; speedup 1.0000x reference)
//
#include <hip/hip_runtime.h>

#define N_USERS 100000
#define N_ITEMS 50000
#define N_NODES 150000
#define EMB 64

// One wave (64 lanes) per edge; lane i owns embedding dim i.
// h_next[row][lane] += val * x[col][lane] via float atomicAdd (device scope).
__global__ void spmm_atomic(const int* __restrict__ rows, const int* __restrict__ cols,
                            const float* __restrict__ vals,
                            const float* __restrict__ xu, const float* __restrict__ xi,
                            float* __restrict__ y, int nedges) {
    int gtid = blockIdx.x * blockDim.x + threadIdx.x;
    int wave = gtid >> 6;
    int lane = threadIdx.x & 63;
    int nwaves = (gridDim.x * blockDim.x) >> 6;
    for (int e = wave; e < nedges; e += nwaves) {
        int r = rows[e];        // uniform across wave -> single broadcast transaction
        int c = cols[e];
        float v = vals[e];
        const float* src = (c < N_USERS) ? (xu + (size_t)c * EMB)
                                         : (xi + (size_t)(c - N_USERS) * EMB);
        atomicAdd(y + (size_t)r * EMB + lane, v * src[lane]);
    }
}

// Final gather: out[0 : B*64]      = 0.25*(user_emb[u] + h1[u] + h2[u] + h3[u])
//               out[B*64 : 2B*64]  = 0.25*(item_emb[i] + h1[N_USERS+i] + ...)
__global__ void gather_out(const int* __restrict__ user, const int* __restrict__ item,
                           const float* __restrict__ ue, const float* __restrict__ ie,
                           const float* __restrict__ h1, const float* __restrict__ h2,
                           const float* __restrict__ h3, float* __restrict__ out, int batch) {
    int wave = (blockIdx.x * blockDim.x + threadIdx.x) >> 6;
    int lane = threadIdx.x & 63;
    if (wave < batch) {
        int u = user[wave];
        size_t n = (size_t)u * EMB + lane;
        out[(size_t)wave * EMB + lane] = 0.25f * (ue[n] + h1[n] + h2[n] + h3[n]);
    } else if (wave < 2 * batch) {
        int b = wave - batch;
        int it = item[b];
        size_t ne = (size_t)it * EMB + lane;              // index into item_emb
        size_t nh = (size_t)(it + N_USERS) * EMB + lane;  // index into h arrays
        out[(size_t)wave * EMB + lane] = 0.25f * (ie[ne] + h1[nh] + h2[nh] + h3[nh]);
    }
}

extern "C" void kernel_launch(void* const* d_in, const int* in_sizes, int n_in,
                              void* d_out, int out_size, void* d_ws, size_t ws_size,
                              hipStream_t stream) {
    const int*   user = (const int*)d_in[0];
    const int*   item = (const int*)d_in[1];
    const int*   rows = (const int*)d_in[2];
    const int*   cols = (const int*)d_in[3];
    const float* vals = (const float*)d_in[4];
    const float* ue   = (const float*)d_in[5];
    const float* ie   = (const float*)d_in[6];
    float*       out  = (float*)d_out;

    const int nedges = in_sizes[2];
    const int batch  = in_sizes[0];

    const size_t hElems = (size_t)N_NODES * EMB;
    float* h1 = (float*)d_ws;
    float* h2 = h1 + hElems;
    float* h3 = h2 + hElems;

    // Zero the three atomic-scatter targets (115.2 MB) in one async memset.
    hipMemsetAsync(d_ws, 0, 3 * hElems * sizeof(float), stream);

    const int threads = 256;
    const int blocks  = 2048;   // 8192 waves = full residency (32 waves/CU x 256 CU)

    // Layer 1: x = ego = concat(user_emb, item_emb), read split (no copy).
    spmm_atomic<<<blocks, threads, 0, stream>>>(rows, cols, vals, ue, ie, h1, nedges);
    // Layer 2: x = h1 (contiguous; "item" half starts at row N_USERS).
    spmm_atomic<<<blocks, threads, 0, stream>>>(rows, cols, vals,
                                                h1, h1 + (size_t)N_USERS * EMB, h2, nedges);
    // Layer 3: x = h2.
    spmm_atomic<<<blocks, threads, 0, stream>>>(rows, cols, vals,
                                                h2, h2 + (size_t)N_USERS * EMB, h3, nedges);

    // Output gather: 2*batch waves.
    const int owaves  = 2 * batch;
    const int oblocks = (owaves * 64 + threads - 1) / threads;
    gather_out<<<oblocks, threads, 0, stream>>>(user, item, ue, ie, h1, h2, h3, out, batch);
}

// Round 2
// 2213.518 us; speedup vs baseline: 1.8110x; 1.8110x over previous
//
#include <hip/hip_runtime.h>

#define N_USERS 100000
#define N_ITEMS 50000
#define N_NODES 150000
#define EMB 64
#define SCAN_BLK 1024

// ---------- counting-sort CSR build ----------

__global__ void hist_kernel(const int* __restrict__ rows, int* __restrict__ cnt, int nedges) {
    int stride = gridDim.x * blockDim.x;
    for (int e = blockIdx.x * blockDim.x + threadIdx.x; e < nedges; e += stride)
        atomicAdd(&cnt[rows[e]], 1);
}

// In-place: data[i] (count) -> block-local exclusive scan; bsum[b] = block total.
__global__ void scan_blocks(int* __restrict__ data, int* __restrict__ bsum, int n) {
    __shared__ int wsum[SCAN_BLK / 64];
    int tid = threadIdx.x, lane = tid & 63, wid = tid >> 6;
    int i = blockIdx.x * SCAN_BLK + tid;
    int v = (i < n) ? data[i] : 0;
    int s = v;
    #pragma unroll
    for (int d = 1; d < 64; d <<= 1) { int t = __shfl_up(s, d); if (lane >= d) s += t; }
    if (lane == 63) wsum[wid] = s;
    __syncthreads();
    if (wid == 0) {
        int w = (lane < SCAN_BLK / 64) ? wsum[lane] : 0;
        #pragma unroll
        for (int d = 1; d < SCAN_BLK / 64; d <<= 1) { int t = __shfl_up(w, d); if (lane >= d) w += t; }
        if (lane < SCAN_BLK / 64) wsum[lane] = w;
    }
    __syncthreads();
    int base = wid ? wsum[wid - 1] : 0;
    int incl = base + s;
    if (i < n) data[i] = incl - v;
    if (tid == SCAN_BLK - 1) bsum[blockIdx.x] = incl;
}

__global__ void add_offsets(int* __restrict__ row_start, int* __restrict__ fill,
                            const int* __restrict__ boff, int n, int nedges) {
    int i = blockIdx.x * blockDim.x + threadIdx.x;
    if (i < n) {
        int v = row_start[i] + boff[i >> 10];
        row_start[i] = v;
        fill[i] = v;
    }
    if (i == 0) row_start[n] = nedges;
}

__global__ void scatter_perm(const int* __restrict__ rows, int* __restrict__ fill,
                             int* __restrict__ perm, int nedges) {
    int stride = gridDim.x * blockDim.x;
    for (int e = blockIdx.x * blockDim.x + threadIdx.x; e < nedges; e += stride) {
        int pos = atomicAdd(&fill[rows[e]], 1);
        perm[pos] = e;
    }
}

// ---------- gather-SpMM: one wave per row, lane = dim ----------

__global__ void spmm_csr(const int* __restrict__ row_start, const int* __restrict__ perm,
                         const int* __restrict__ cols, const float* __restrict__ vals,
                         const float* __restrict__ xu, const float* __restrict__ xi,
                         float* __restrict__ y) {
    int lane = threadIdx.x & 63;
    int wave = (blockIdx.x * blockDim.x + threadIdx.x) >> 6;
    int nw = (gridDim.x * blockDim.x) >> 6;
    for (int r = wave; r < N_NODES; r += nw) {
        int s = row_start[r], e = row_start[r + 1];
        float acc = 0.f;
        for (int k = s; k < e; k += 64) {
            int kk = k + lane;
            int c = 0; float v = 0.f;
            if (kk < e) { int p = perm[kk]; c = cols[p]; v = vals[p]; }
            int cnt = min(64, e - k);
            int j = 0;
            for (; j + 4 <= cnt; j += 4) {
                int c0 = __shfl(c, j), c1 = __shfl(c, j + 1), c2 = __shfl(c, j + 2), c3 = __shfl(c, j + 3);
                float v0 = __shfl(v, j), v1 = __shfl(v, j + 1), v2 = __shfl(v, j + 2), v3 = __shfl(v, j + 3);
                const float* s0 = (c0 < N_USERS) ? (xu + (size_t)c0 * EMB) : (xi + (size_t)(c0 - N_USERS) * EMB);
                const float* s1 = (c1 < N_USERS) ? (xu + (size_t)c1 * EMB) : (xi + (size_t)(c1 - N_USERS) * EMB);
                const float* s2 = (c2 < N_USERS) ? (xu + (size_t)c2 * EMB) : (xi + (size_t)(c2 - N_USERS) * EMB);
                const float* s3 = (c3 < N_USERS) ? (xu + (size_t)c3 * EMB) : (xi + (size_t)(c3 - N_USERS) * EMB);
                float x0 = s0[lane], x1 = s1[lane], x2 = s2[lane], x3 = s3[lane];
                acc = fmaf(v0, x0, acc);
                acc = fmaf(v1, x1, acc);
                acc = fmaf(v2, x2, acc);
                acc = fmaf(v3, x3, acc);
            }
            for (; j < cnt; ++j) {
                int cj = __shfl(c, j);
                float vj = __shfl(v, j);
                const float* sj = (cj < N_USERS) ? (xu + (size_t)cj * EMB) : (xi + (size_t)(cj - N_USERS) * EMB);
                acc = fmaf(vj, sj[lane], acc);
            }
        }
        y[(size_t)r * EMB + lane] = acc;
    }
}

// ---------- batch-row output accumulation ----------

__global__ void out_init(const int* __restrict__ user, const int* __restrict__ item,
                         const float* __restrict__ ue, const float* __restrict__ ie,
                         float* __restrict__ out, int batch) {
    int wave = (blockIdx.x * blockDim.x + threadIdx.x) >> 6;
    int lane = threadIdx.x & 63;
    if (wave < batch)
        out[(size_t)wave * EMB + lane] = ue[(size_t)user[wave] * EMB + lane];
    else if (wave < 2 * batch)
        out[(size_t)wave * EMB + lane] = ie[(size_t)item[wave - batch] * EMB + lane];
}

__global__ void out_add(const int* __restrict__ user, const int* __restrict__ item,
                        const float* __restrict__ h, float* __restrict__ out,
                        int batch, float scale) {
    int wave = (blockIdx.x * blockDim.x + threadIdx.x) >> 6;
    int lane = threadIdx.x & 63;
    if (wave < 2 * batch) {
        int node = (wave < batch) ? user[wave] : (N_USERS + item[wave - batch]);
        size_t o = (size_t)wave * EMB + lane;
        out[o] = (out[o] + h[(size_t)node * EMB + lane]) * scale;
    }
}

// ---------- driver ----------

extern "C" void kernel_launch(void* const* d_in, const int* in_sizes, int n_in,
                              void* d_out, int out_size, void* d_ws, size_t ws_size,
                              hipStream_t stream) {
    const int*   user = (const int*)d_in[0];
    const int*   item = (const int*)d_in[1];
    const int*   rows = (const int*)d_in[2];
    const int*   cols = (const int*)d_in[3];
    const float* vals = (const float*)d_in[4];
    const float* ue   = (const float*)d_in[5];
    const float* ie   = (const float*)d_in[6];
    float*       out  = (float*)d_out;

    const int nedges = in_sizes[2];
    const int batch  = in_sizes[0];

    // workspace layout (all 256B-aligned)
    const size_t hBytes  = (size_t)N_NODES * EMB * sizeof(float);  // 38,400,000
    const size_t pBytes  = (size_t)6400000 * sizeof(int);          // 25,600,000 (nedges)
    const size_t rsBytes = 600064;                                 // 150001 ints padded
    char* p = (char*)d_ws;
    float* hA       = (float*)p;              p += hBytes;
    float* hB       = (float*)p;              p += hBytes;
    int*   perm     = (int*)p;                p += pBytes;
    int*   row_start= (int*)p;                p += rsBytes;
    int*   fill     = (int*)p;                p += rsBytes;
    int*   bsum     = (int*)p;                p += 1024;
    int*   dummy    = (int*)p;                p += 1024;

    const int threads = 256;
    const int blocks  = 2048;  // 8192 waves

    // --- CSR build ---
    hipMemsetAsync(row_start, 0, rsBytes, stream);
    hist_kernel<<<blocks, threads, 0, stream>>>(rows, row_start, nedges);
    const int nscan = (N_NODES + SCAN_BLK - 1) / SCAN_BLK;  // 147
    scan_blocks<<<nscan, SCAN_BLK, 0, stream>>>(row_start, bsum, N_NODES);
    scan_blocks<<<1, SCAN_BLK, 0, stream>>>(bsum, dummy, nscan);   // exclusive scan of block sums
    add_offsets<<<(N_NODES + threads - 1) / threads, threads, 0, stream>>>(
        row_start, fill, bsum, N_NODES, nedges);
    scatter_perm<<<blocks, threads, 0, stream>>>(rows, fill, perm, nedges);

    // --- out = ego[sel] ---
    const int owaves  = 2 * batch;
    const int oblocks = (owaves * 64 + threads - 1) / threads;
    out_init<<<oblocks, threads, 0, stream>>>(user, item, ue, ie, out, batch);

    // --- 3 propagation layers, accumulating selected rows into out ---
    spmm_csr<<<blocks, threads, 0, stream>>>(row_start, perm, cols, vals, ue, ie, hA);
    out_add<<<oblocks, threads, 0, stream>>>(user, item, hA, out, batch, 1.0f);

    spmm_csr<<<blocks, threads, 0, stream>>>(row_start, perm, cols, vals,
                                             hA, hA + (size_t)N_USERS * EMB, hB);
    out_add<<<oblocks, threads, 0, stream>>>(user, item, hB, out, batch, 1.0f);

    spmm_csr<<<blocks, threads, 0, stream>>>(row_start, perm, cols, vals,
                                             hB, hB + (size_t)N_USERS * EMB, hA);
    out_add<<<oblocks, threads, 0, stream>>>(user, item, hA, out, batch, 0.25f);
}